// Round 5
// baseline (1164.404 us; speedup 1.0000x reference)
//
#include <hip/hip_runtime.h>

typedef unsigned short u16;
typedef unsigned int   u32;
typedef unsigned long long u64;

__device__ __forceinline__ float b2f(u16 u) {
    union { u32 i; float f; } v; v.i = ((u32)u) << 16; return v.f;
}
__device__ __forceinline__ u16 f2b(float f) {
    union { float f; u32 i; } v; v.f = f;
    u32 x = v.i;
    x += 0x7fffu + ((x >> 16) & 1u);   // RNE
    return (u16)(x >> 16);
}

template<bool BF> __device__ __forceinline__ float LD(const void* p, int i) {
    if (BF) return b2f(((const u16*)p)[i]);
    return ((const float*)p)[i];
}
template<bool BF> __device__ __forceinline__ float4 LD4(const void* p, int i) {
    if (BF) {
        ushort4 v = *(const ushort4*)((const u16*)p + i);   // 8B, i%4==0 -> aligned
        return make_float4(b2f(v.x), b2f(v.y), b2f(v.z), b2f(v.w));
    }
    return *(const float4*)((const float*)p + i);
}

// On-device dtype sniff: for bf16 data, each u32 word's low u16 is a bf16
// value whose exponent lies in a narrow band (or exact zero). For fp32 data
// the low u16 is a ~uniform mantissa tail (~7% band hit). 64-sample ballot.
__device__ __forceinline__ bool detect_bf16(const void* p) {
    u32 w = ((const u32*)p)[threadIdx.x & 63];
    u16 lo = (u16)(w & 0xFFFFu);
    int e = (lo >> 7) & 0xFF;
    bool hit = (lo == 0) || (e >= 0x70 && e <= 0x82);   // |x| in [2^-15, 8] or 0
    u64 m = __ballot(hit);
    return __popcll(m) >= 32;
}

// ---------------------------------------------------------------------------
// One WG = 16 batch rows (48 pair-rows), 256 threads. Thread tile 4c x 12r.
// Activation reads are wave-uniform LDS broadcasts; weight reads are lane-
// coalesced float4 rows from global (L2-resident). h/S in bf16 LDS.
// ---------------------------------------------------------------------------
template<bool BA>
__device__ __forceinline__ void gather_phase(
    float* inp_lds, const void* obs, const void* ag, const void* g,
    const void* anchor, const void* act, int wg, int B)
{
    int t = threadIdx.x;
    if (t < 48) {
        const int O1[3] = {0, 0, 1}, O2[3] = {1, 2, 2};
        const int JA[3] = {3, 4, 6}, KA[3] = {5, 7, 8};
        int p = t / 16, bl = t % 16;
        int b = wg * 16 + bl; if (b >= B) b = B - 1;
        int j = JA[p], k = KA[p];
        bool sel = (LD<BA>(anchor, b * 9 + j) - LD<BA>(anchor, b * 9 + k)) >= 0.0f;
        int bit2 = sel ? j : k;
        int oi = sel ? O1[p] : O2[p];
        int oj = sel ? O2[p] : O1[p];
        float* row = &inp_lds[t * 56];
        row[0] = LD<BA>(ag, b * 9 + p);
        row[1] = LD<BA>(ag, b * 9 + bit2);
        row[2] = LD<BA>(g, b * 9 + p);
        row[3] = LD<BA>(g, b * 9 + bit2);
        for (int c = 0; c < 10; ++c) row[4 + c] = LD<BA>(obs, b * 55 + c);
        row[14] = (oi == 0) ? 1.f : 0.f;
        row[15] = (oi == 1) ? 1.f : 0.f;
        row[16] = (oi == 2) ? 1.f : 0.f;
        for (int c = 0; c < 15; ++c) row[17 + c] = LD<BA>(obs, b * 55 + 10 + 15 * oi + c);
        row[32] = (oj == 0) ? 1.f : 0.f;
        row[33] = (oj == 1) ? 1.f : 0.f;
        row[34] = (oj == 2) ? 1.f : 0.f;
        for (int c = 0; c < 15; ++c) row[35 + c] = LD<BA>(obs, b * 55 + 10 + 15 * oj + c);
        for (int c = 0; c < 4; ++c)  row[50 + c] = LD<BA>(act, b * 4 + c);
    }
}

template<bool BW>
__device__ __forceinline__ void nets_phase(
    const float* inp_lds, u16* h_lds, u16* s_lds,
    const void* w1, const void* b1, const void* w2, const void* b2,
    const void* w3, const void* b3, const void* w4, const void* b4)
{
    int t = threadIdx.x;
    int cg = t & 63, rg = t >> 6;
    int c0 = cg * 4;
    for (int net = 0; net < 2; ++net) {
        const void* W1 = net ? w3 : w1;
        const void* B1 = net ? b3 : b1;
        const void* W2 = net ? w4 : w2;
        const void* B2 = net ? b4 : b2;

        // Layer 1: (48 x 54) @ (54 x 256)
        float acc[12][4];
        #pragma unroll
        for (int i = 0; i < 12; ++i)
            #pragma unroll
            for (int c = 0; c < 4; ++c) acc[i][c] = 0.f;
        for (int k = 0; k < 54; ++k) {
            float4 wv = LD4<BW>(W1, k * 256 + c0);
            #pragma unroll
            for (int i = 0; i < 12; ++i) {
                float a = inp_lds[(rg * 12 + i) * 56 + k];   // wave-broadcast
                acc[i][0] += a * wv.x; acc[i][1] += a * wv.y;
                acc[i][2] += a * wv.z; acc[i][3] += a * wv.w;
            }
        }
        {
            float bb[4] = {LD<BW>(B1, c0), LD<BW>(B1, c0 + 1),
                           LD<BW>(B1, c0 + 2), LD<BW>(B1, c0 + 3)};
            #pragma unroll
            for (int i = 0; i < 12; ++i)
                #pragma unroll
                for (int c = 0; c < 4; ++c)
                    h_lds[(rg * 12 + i) * 256 + c0 + c] =
                        f2b(fmaxf(acc[i][c] + bb[c], 0.f));
        }
        __syncthreads();

        // Layer 2: (48 x 256) @ (256 x 256)
        float acc2[12][4];
        #pragma unroll
        for (int i = 0; i < 12; ++i)
            #pragma unroll
            for (int c = 0; c < 4; ++c) acc2[i][c] = 0.f;
        for (int k = 0; k < 256; ++k) {
            float4 wv = LD4<BW>(W2, k * 256 + c0);
            #pragma unroll
            for (int i = 0; i < 12; ++i) {
                float a = b2f(h_lds[(rg * 12 + i) * 256 + k]);  // wave-broadcast
                acc2[i][0] += a * wv.x; acc2[i][1] += a * wv.y;
                acc2[i][2] += a * wv.z; acc2[i][3] += a * wv.w;
            }
        }
        // In-place overwrite safe: wave owns rows rg*12..+11 for reads+writes.
        {
            float bb[4] = {LD<BW>(B2, c0), LD<BW>(B2, c0 + 1),
                           LD<BW>(B2, c0 + 2), LD<BW>(B2, c0 + 3)};
            #pragma unroll
            for (int i = 0; i < 12; ++i)
                #pragma unroll
                for (int c = 0; c < 4; ++c)
                    h_lds[(rg * 12 + i) * 256 + c0 + c] =
                        f2b(fmaxf(acc2[i][c] + bb[c], 0.f));
        }
        __syncthreads();

        // Pair-sum: S[b][c] = sum_p x2[p*16+b][c]
        {
            int b = t >> 4;
            int cc0 = (t & 15) * 16;
            for (int cc = 0; cc < 16; ++cc) {
                float s = b2f(h_lds[(0 * 16 + b) * 256 + cc0 + cc])
                        + b2f(h_lds[(1 * 16 + b) * 256 + cc0 + cc])
                        + b2f(h_lds[(2 * 16 + b) * 256 + cc0 + cc]);
                s_lds[net * 4096 + b * 256 + cc0 + cc] = f2b(s);
            }
        }
        __syncthreads();
    }
}

template<bool BW>
__device__ __forceinline__ void rho_phase(
    u16* h_lds, const u16* s_lds,
    const void* w5, const void* b5, const void* w7, const void* b7)
{
    int t = threadIdx.x;
    int cg = t & 63, rg = t >> 6;
    int c0 = cg * 4;
    for (int net = 0; net < 2; ++net) {
        const void* WR = net ? w7 : w5;
        const void* BR = net ? b7 : b5;
        float racc[4][4];
        #pragma unroll
        for (int i = 0; i < 4; ++i)
            #pragma unroll
            for (int c = 0; c < 4; ++c) racc[i][c] = 0.f;
        for (int k = 0; k < 256; ++k) {
            float4 wv = LD4<BW>(WR, k * 256 + c0);
            #pragma unroll
            for (int i = 0; i < 4; ++i) {
                float a = b2f(s_lds[net * 4096 + (rg * 4 + i) * 256 + k]);
                racc[i][0] += a * wv.x; racc[i][1] += a * wv.y;
                racc[i][2] += a * wv.z; racc[i][3] += a * wv.w;
            }
        }
        {
            float bb[4] = {LD<BW>(BR, c0), LD<BW>(BR, c0 + 1),
                           LD<BW>(BR, c0 + 2), LD<BW>(BR, c0 + 3)};
            #pragma unroll
            for (int i = 0; i < 4; ++i)
                #pragma unroll
                for (int c = 0; c < 4; ++c)
                    h_lds[(net * 16 + rg * 4 + i) * 256 + c0 + c] =
                        f2b(fmaxf(racc[i][c] + bb[c], 0.f));
        }
    }
}

__global__ __launch_bounds__(256, 3) void critic_adaptive(
    const void* obs, const void* ag, const void* g, const void* anchor,
    const void* act,
    const void* w1, const void* b1, const void* w2, const void* b2,
    const void* w3, const void* b3, const void* w4, const void* b4,
    const void* w5, const void* b5, const void* w6, const void* b6,
    const void* w7, const void* b7, const void* w8, const void* b8,
    float* __restrict__ out, int B)
{
    __shared__ float inp_lds[48 * 56];
    __shared__ u16   h_lds[48 * 256];
    __shared__ u16   s_lds[2 * 16 * 256];

    const int t  = threadIdx.x;
    const int wg = blockIdx.x;

    // Block-uniform dtype flags (identical across all waves/blocks).
    bool Fa = detect_bf16(obs);
    bool Fw = detect_bf16(w1);
    bool Fv = detect_bf16(w6);

    if (Fa) gather_phase<true >(inp_lds, obs, ag, g, anchor, act, wg, B);
    else    gather_phase<false>(inp_lds, obs, ag, g, anchor, act, wg, B);
    __syncthreads();

    if (Fw) nets_phase<true >(inp_lds, h_lds, s_lds, w1, b1, w2, b2, w3, b3, w4, b4);
    else    nets_phase<false>(inp_lds, h_lds, s_lds, w1, b1, w2, b2, w3, b3, w4, b4);

    if (Fw) rho_phase<true >(h_lds, s_lds, w5, b5, w7, b7);
    else    rho_phase<false>(h_lds, s_lds, w5, b5, w7, b7);
    __syncthreads();

    // Final dots: q = rhoH @ w6 + b6 (16 rows per net). FP32 OUTPUT.
    if (t < 32) {
        int net = t >> 4, r = t & 15;
        const void* wv = net ? w8 : w6;
        const void* bv = net ? b8 : b6;
        float q = Fv ? b2f(((const u16*)bv)[0]) : ((const float*)bv)[0];
        for (int k = 0; k < 256; ++k) {
            float wk = Fv ? b2f(((const u16*)wv)[k]) : ((const float*)wv)[k];
            q += b2f(h_lds[(net * 16 + r) * 256 + k]) * wk;
        }
        int row = wg * 16 + r;
        if (row < B) out[net * B + row] = q;
    }
}

extern "C" void kernel_launch(void* const* d_in, const int* in_sizes, int n_in,
                              void* d_out, int out_size, void* d_ws, size_t ws_size,
                              hipStream_t stream) {
    const void *obs, *ag, *g, *anc, *act;
    const void *w1, *b1, *w2, *b2, *w3, *b3, *w4, *b4;
    const void *w5, *b5, *w6, *b6, *w7, *b7, *w8, *b8;
    int B;

    // Order detection: dict order has w1 (54*256=13824 elems) at slot 5;
    // alphabetical (act,ag,anchor_g,b1..b8,g,obs,w1..w8) has b3 (256) there.
    bool dict = (n_in >= 21) && (in_sizes[5] == 13824);
    if (dict) {
        obs = d_in[0];  ag = d_in[1];  g  = d_in[2];  anc = d_in[3]; act = d_in[4];
        w1 = d_in[5];   b1 = d_in[6];  w2 = d_in[7];  b2 = d_in[8];
        w3 = d_in[9];   b3 = d_in[10]; w4 = d_in[11]; b4 = d_in[12];
        w5 = d_in[13];  b5 = d_in[14]; w6 = d_in[15]; b6 = d_in[16];
        w7 = d_in[17];  b7 = d_in[18]; w8 = d_in[19]; b8 = d_in[20];
        B = in_sizes[0] / 55;
    } else {
        act = d_in[0];  ag = d_in[1];  anc = d_in[2];
        b1 = d_in[3];   b2 = d_in[4];  b3 = d_in[5];  b4 = d_in[6];
        b5 = d_in[7];   b6 = d_in[8];  b7 = d_in[9];  b8 = d_in[10];
        g  = d_in[11];  obs = d_in[12];
        w1 = d_in[13];  w2 = d_in[14]; w3 = d_in[15]; w4 = d_in[16];
        w5 = d_in[17];  w6 = d_in[18]; w7 = d_in[19]; w8 = d_in[20];
        B = in_sizes[12] / 55;
    }
    float* out = (float*)d_out;

    int grid = (B + 15) / 16;
    critic_adaptive<<<grid, 256, 0, stream>>>(obs, ag, g, anc, act,
                                              w1, b1, w2, b2, w3, b3, w4, b4,
                                              w5, b5, w6, b6, w7, b7, w8, b8,
                                              out, B);
}

// Round 6
// 219.064 us; speedup vs baseline: 5.3154x; 5.3154x over previous
//
#include <hip/hip_runtime.h>

typedef unsigned short u16;
typedef unsigned int   u32;

using bf8 = __attribute__((ext_vector_type(8))) __bf16;
using f4  = __attribute__((ext_vector_type(4))) float;

__device__ __forceinline__ float b2f(u16 u) {
    union { u32 i; float f; } v; v.i = ((u32)u) << 16; return v.f;
}
__device__ __forceinline__ u16 f2b(float f) {
    union { float f; u32 i; } v; v.f = f;
    u32 x = v.i;
    x += 0x7fffu + ((x >> 16) & 1u);   // RNE
    return (u16)(x >> 16);
}

// ---------------------------------------------------------------------------
// Weight swizzle + fp32->bf16: pack W (K x 256 row-major, fp32) into MFMA-B-
// fragment-linear bf16 layout:
// dst[((kt*16+ct)*64+lane)*8+j] = bf16(W[kt*32+(lane>>4)*8+j][ct*16+(lane&15)])
// zero-padded past kmax. One block per (kt,ct) tile of one matrix.
// Layout verified end-to-end (rounds 2/3 bit-identical outputs).
// ---------------------------------------------------------------------------
__global__ void swz_all(const float* __restrict__ w1, const float* __restrict__ w3,
                        const float* __restrict__ w2, const float* __restrict__ w4,
                        const float* __restrict__ w5, const float* __restrict__ w7,
                        u16* __restrict__ ws) {
    int bid = blockIdx.x;               // 0..575
    const float* src; u16* dst; int kmax; int rel;
    if      (bid <  32) { src = w1; dst = ws;          kmax = 54;  rel = bid;       }
    else if (bid <  64) { src = w3; dst = ws + 16384;  kmax = 54;  rel = bid - 32;  }
    else if (bid < 192) { src = w2; dst = ws + 32768;  kmax = 256; rel = bid - 64;  }
    else if (bid < 320) { src = w4; dst = ws + 98304;  kmax = 256; rel = bid - 192; }
    else if (bid < 448) { src = w5; dst = ws + 163840; kmax = 256; rel = bid - 320; }
    else                { src = w7; dst = ws + 229376; kmax = 256; rel = bid - 448; }
    int kt = rel >> 4, ct = rel & 15, lane = threadIdx.x;
    int n = ct * 16 + (lane & 15);
    int kbase = kt * 32 + (lane >> 4) * 8;
    u16* d = dst + (size_t)(rel * 64 + lane) * 8;
    #pragma unroll
    for (int j = 0; j < 8; ++j) {
        int k = kbase + j;
        d[j] = (k < kmax) ? f2b(src[k * 256 + n]) : (u16)0;
    }
}

// ---------------------------------------------------------------------------
// Fused critic kernel. One WG = 32 batch rows (96 phi rows). 4 waves.
// LDS: inp 96x72 bf16 (13824B) + h 96x264 bf16 (50688B) = 64512 B -> 2 WG/CU.
// After both nets, h region is reused: S1 [0,8448), S2 [8448,16896),
// rho-h scratch [16896,25344) / [0,8448) (elements).
// MFMA mappings (guide-verified): A[m=lane&15][k=(lane>>4)*8+j];
// C/D col=lane&15, row=(lane>>4)*4+reg.
// ---------------------------------------------------------------------------
__global__ __launch_bounds__(256, 2) void critic_kernel(
    const float* __restrict__ obs, const float* __restrict__ ag,
    const float* __restrict__ g,   const float* __restrict__ anchor,
    const float* __restrict__ act,
    const float* __restrict__ b1,  const float* __restrict__ b2,
    const float* __restrict__ b3,  const float* __restrict__ b4,
    const float* __restrict__ b5,  const float* __restrict__ b7,
    const float* __restrict__ w6,  const float* __restrict__ b6,
    const float* __restrict__ w8,  const float* __restrict__ b8,
    const u16* __restrict__ wsz, float* __restrict__ out, int B) {

    __shared__ u16 inp_lds[96 * 72];
    __shared__ u16 h_lds[96 * 264];

    const int t    = threadIdx.x;
    const int lane = t & 63;
    const int wave = t >> 6;
    const int lr   = lane & 15;   // A-row / B-col / C-col within tile
    const int lg   = lane >> 4;   // k-group (A/B), row-group (C/D)
    const int wg   = blockIdx.x;

    // ---- Phase 0: build pair inputs (3 pairs x 32 rows x 54 cols, pad to 72)
    if (t < 96) {
        const int O1[3] = {0, 0, 1}, O2[3] = {1, 2, 2};
        const int JA[3] = {3, 4, 6}, KA[3] = {5, 7, 8};
        int p = t / 32, bl = t % 32;
        int b = wg * 32 + bl;
        int j = JA[p], k = KA[p];
        bool sel = (anchor[b * 9 + j] - anchor[b * 9 + k]) >= 0.0f;
        int bit2 = sel ? j : k;
        int oi = sel ? O1[p] : O2[p];
        int oj = sel ? O2[p] : O1[p];
        u16* row = &inp_lds[t * 72];
        row[0] = f2b(ag[b * 9 + p]);
        row[1] = f2b(ag[b * 9 + bit2]);
        row[2] = f2b(g[b * 9 + p]);
        row[3] = f2b(g[b * 9 + bit2]);
        for (int c = 0; c < 10; ++c) row[4 + c] = f2b(obs[b * 55 + c]);
        const u16 ONE = 0x3F80;  // 1.0 bf16
        row[14] = (oi == 0) ? ONE : 0; row[15] = (oi == 1) ? ONE : 0; row[16] = (oi == 2) ? ONE : 0;
        for (int c = 0; c < 15; ++c) row[17 + c] = f2b(obs[b * 55 + 10 + 15 * oi + c]);
        row[32] = (oj == 0) ? ONE : 0; row[33] = (oj == 1) ? ONE : 0; row[34] = (oj == 2) ? ONE : 0;
        for (int c = 0; c < 15; ++c) row[35 + c] = f2b(obs[b * 55 + 10 + 15 * oj + c]);
        for (int c = 0; c < 4; ++c)  row[50 + c] = f2b(act[b * 4 + c]);
        for (int c = 54; c < 72; ++c) row[c] = 0;
    }
    __syncthreads();

    f4  sacc[2][4];      // net1 (S2) pair-sums, fp32
    u32 s1p[2][4][2];    // net0 (S1) pair-sums, packed bf16

    // ---- Phi networks (net 0: w1/w2, net 1: w3/w4)
    for (int net = 0; net < 2; ++net) {
        const u16* Wl1 = wsz + (net ? 16384 : 0);
        const u16* Wl2 = wsz + 32768 + (net ? 65536 : 0);
        const float* bl1 = net ? b3 : b1;
        const float* bl2 = net ? b4 : b2;

        // Layer 1: (96 x 64) @ (64 x 256)
        f4 acc[6][4];
        #pragma unroll
        for (int rt = 0; rt < 6; ++rt)
            #pragma unroll
            for (int c = 0; c < 4; ++c) acc[rt][c] = (f4){0.f, 0.f, 0.f, 0.f};
        #pragma unroll
        for (int kt = 0; kt < 2; ++kt) {
            bf8 bfr[4];
            #pragma unroll
            for (int c = 0; c < 4; ++c)
                bfr[c] = *(const bf8*)(Wl1 + (size_t)(((kt * 16 + wave * 4 + c) * 64 + lane) * 8));
            #pragma unroll
            for (int rt = 0; rt < 6; ++rt) {
                bf8 afr = *(const bf8*)(&inp_lds[(rt * 16 + lr) * 72 + kt * 32 + lg * 8]);
                #pragma unroll
                for (int c = 0; c < 4; ++c)
                    acc[rt][c] = __builtin_amdgcn_mfma_f32_16x16x32_bf16(afr, bfr[c], acc[rt][c], 0, 0, 0);
            }
        }
        #pragma unroll
        for (int c = 0; c < 4; ++c) {
            float bias = bl1[(wave * 4 + c) * 16 + lr];
            #pragma unroll
            for (int rt = 0; rt < 6; ++rt)
                #pragma unroll
                for (int r = 0; r < 4; ++r) {
                    float x = acc[rt][c][r] + bias;
                    h_lds[(rt * 16 + lg * 4 + r) * 264 + (wave * 4 + c) * 16 + lr] = f2b(fmaxf(x, 0.f));
                }
        }
        __syncthreads();

        // Layer 2: (96 x 256) @ (256 x 256), relu, pair-sum
        f4 acc2[6][4];
        #pragma unroll
        for (int rt = 0; rt < 6; ++rt)
            #pragma unroll
            for (int c = 0; c < 4; ++c) acc2[rt][c] = (f4){0.f, 0.f, 0.f, 0.f};
        #pragma unroll
        for (int ks = 0; ks < 8; ++ks) {
            bf8 bfr[4];
            #pragma unroll
            for (int c = 0; c < 4; ++c)
                bfr[c] = *(const bf8*)(Wl2 + (size_t)(((ks * 16 + wave * 4 + c) * 64 + lane) * 8));
            #pragma unroll
            for (int rt = 0; rt < 6; ++rt) {
                bf8 afr = *(const bf8*)(&h_lds[(rt * 16 + lr) * 264 + ks * 32 + lg * 8]);
                #pragma unroll
                for (int c = 0; c < 4; ++c)
                    acc2[rt][c] = __builtin_amdgcn_mfma_f32_16x16x32_bf16(afr, bfr[c], acc2[rt][c], 0, 0, 0);
            }
        }
        #pragma unroll
        for (int c = 0; c < 4; ++c) {
            float bias = bl2[(wave * 4 + c) * 16 + lr];
            #pragma unroll
            for (int s = 0; s < 2; ++s) {
                f4 sv = (f4){0.f, 0.f, 0.f, 0.f};
                #pragma unroll
                for (int p = 0; p < 3; ++p)
                    #pragma unroll
                    for (int r = 0; r < 4; ++r)
                        sv[r] += fmaxf(acc2[p * 2 + s][c][r] + bias, 0.f);
                if (net == 0) {
                    s1p[s][c][0] = (u32)f2b(sv[0]) | ((u32)f2b(sv[1]) << 16);
                    s1p[s][c][1] = (u32)f2b(sv[2]) | ((u32)f2b(sv[3]) << 16);
                } else {
                    sacc[s][c] = sv;
                }
            }
        }
        __syncthreads();  // H reads done before next net overwrites H
    }

    // ---- Write S1, S2 into (now free) h region
    #pragma unroll
    for (int s = 0; s < 2; ++s)
        #pragma unroll
        for (int c = 0; c < 4; ++c) {
            int col = (wave * 4 + c) * 16 + lr;
            #pragma unroll
            for (int r = 0; r < 4; ++r) {
                int rowo = (s * 16 + lg * 4 + r) * 264 + col;
                h_lds[rowo]        = (u16)(s1p[s][c][r >> 1] >> ((r & 1) * 16));
                h_lds[8448 + rowo] = f2b(sacc[s][c][r]);
            }
        }
    __syncthreads();

    // ---- Rho heads (net 0: w5/w6 from S1, net 1: w7/w8 from S2)
    for (int net = 0; net < 2; ++net) {
        const u16* Wr = wsz + 163840 + net * 65536;
        const float* br = net ? b7 : b5;
        const int soff = net ? 8448 : 0;
        const int hoff = net ? 0 : 16896;   // net1's h overwrites consumed S1
        f4 racc[2][4];
        #pragma unroll
        for (int rt = 0; rt < 2; ++rt)
            #pragma unroll
            for (int c = 0; c < 4; ++c) racc[rt][c] = (f4){0.f, 0.f, 0.f, 0.f};
        #pragma unroll
        for (int ks = 0; ks < 8; ++ks) {
            bf8 bfr[4];
            #pragma unroll
            for (int c = 0; c < 4; ++c)
                bfr[c] = *(const bf8*)(Wr + (size_t)(((ks * 16 + wave * 4 + c) * 64 + lane) * 8));
            #pragma unroll
            for (int rt = 0; rt < 2; ++rt) {
                bf8 afr = *(const bf8*)(&h_lds[soff + (rt * 16 + lr) * 264 + ks * 32 + lg * 8]);
                #pragma unroll
                for (int c = 0; c < 4; ++c)
                    racc[rt][c] = __builtin_amdgcn_mfma_f32_16x16x32_bf16(afr, bfr[c], racc[rt][c], 0, 0, 0);
            }
        }
        #pragma unroll
        for (int c = 0; c < 4; ++c) {
            float bias = br[(wave * 4 + c) * 16 + lr];
            #pragma unroll
            for (int rt = 0; rt < 2; ++rt)
                #pragma unroll
                for (int r = 0; r < 4; ++r) {
                    float x = fmaxf(racc[rt][c][r] + bias, 0.f);
                    h_lds[hoff + (rt * 16 + lg * 4 + r) * 264 + (wave * 4 + c) * 16 + lr] = f2b(x);
                }
        }
        __syncthreads();
    }

    // ---- Final dots: q = rhoH @ w6 + b6 (rows 0..31 per net). FP32 OUTPUT.
    if (t < 64) {
        int net = t >> 5, r = t & 31;
        const float* wv = net ? w8 : w6;
        const int hoff = net ? 0 : 16896;
        float q = net ? b8[0] : b6[0];
        #pragma unroll 8
        for (int kk = 0; kk < 256; ++kk)
            q += b2f(h_lds[hoff + r * 264 + kk]) * wv[kk];
        out[net * B + wg * 32 + r] = q;
    }
}

extern "C" void kernel_launch(void* const* d_in, const int* in_sizes, int n_in,
                              void* d_out, int out_size, void* d_ws, size_t ws_size,
                              hipStream_t stream) {
    const float* obs = (const float*)d_in[0];
    const float* ag  = (const float*)d_in[1];
    const float* g   = (const float*)d_in[2];
    const float* anc = (const float*)d_in[3];
    const float* act = (const float*)d_in[4];
    const float* w1  = (const float*)d_in[5];
    const float* b1  = (const float*)d_in[6];
    const float* w2  = (const float*)d_in[7];
    const float* b2  = (const float*)d_in[8];
    const float* w3  = (const float*)d_in[9];
    const float* b3  = (const float*)d_in[10];
    const float* w4  = (const float*)d_in[11];
    const float* b4  = (const float*)d_in[12];
    const float* w5  = (const float*)d_in[13];
    const float* b5  = (const float*)d_in[14];
    const float* w6  = (const float*)d_in[15];
    const float* b6  = (const float*)d_in[16];
    const float* w7  = (const float*)d_in[17];
    const float* b7  = (const float*)d_in[18];
    const float* w8  = (const float*)d_in[19];
    const float* b8  = (const float*)d_in[20];
    u16* ws   = (u16*)d_ws;
    float* out = (float*)d_out;
    int B = in_sizes[0] / 55;

    // 576 blocks: w1(32) w3(32) w2(128) w4(128) w5(128) w7(128)
    swz_all<<<576, 64, 0, stream>>>(w1, w3, w2, w4, w5, w7, ws);
    critic_kernel<<<(B + 31) / 32, 256, 0, stream>>>(obs, ag, g, anc, act,
                                                     b1, b2, b3, b4, b5, b7,
                                                     w6, b6, w8, b8, ws, out, B);
}